// Round 18
// baseline (133.043 us; speedup 1.0000x reference)
//
#include <hip/hip_runtime.h>

// CoPE2d: B=64, NH=16, Wh=Ww=16, N=256, C=64, NPOS=288, BH=1024
// R18 = R17 (4-wave/4-step pipeline, dbuf f32 L-table, raw barrier, float4
// phase D, nt stores) + NON-TEMPORAL query loads: gates (256 MB = L3 size)
// get L3 residency priority; query (64 MB, prefetch-hidden) streams from HBM.

#define NPOS 288
#define NT   18
#define LTSF 292         // f32 Ltab row stride (padded)

typedef __attribute__((ext_vector_type(8))) short bf16x8;
typedef __attribute__((ext_vector_type(4))) float f32x4;

__device__ __forceinline__ unsigned short f2bf(float f) {
    unsigned u = __float_as_uint(f);
    u += 0x7FFF + ((u >> 16) & 1);
    return (unsigned short)(u >> 16);
}
__device__ __forceinline__ unsigned cvt_pk_bf16(float lo, float hi) {
    unsigned r;                       // plain-loaded inputs only (R13 lesson)
    asm("v_cvt_pk_bf16_f32 %0, %1, %2" : "=v"(r) : "v"(lo), "v"(hi));
    return r;
}
__device__ __forceinline__ float fast_exp2(float x) {
    float r; asm("v_exp_f32 %0, %1" : "=v"(r) : "v"(x)); return r;
}
__device__ __forceinline__ float fast_fract(float x) {
    float r; asm("v_fract_f32 %0, %1" : "=v"(r) : "v"(x)); return r;
}
__device__ __forceinline__ float sigmoid_f(float x) {
    return __builtin_amdgcn_rcpf(1.0f + fast_exp2(x * -1.44269504088896f));
}
// row_shl:D within 16-lane DPP rows, 0 beyond row end.
template <int D>
__device__ __forceinline__ float row_shl(float v) {
    int s = __builtin_amdgcn_update_dpp(0, __float_as_int(v), 0x100 | D, 0xF, 0xF, true);
    return __int_as_float(s);
}

// ---- prep: pos_emb (64x288 f32) -> bf16 B-fragments in ws ------------------
__global__ void prep_kernel(const float* __restrict__ pos_emb,
                            short* __restrict__ wsb) {
    int idx = blockIdx.x * blockDim.x + threadIdx.x;
    if (idx >= NT * 2 * 64) return;
    int l = idx & 63;
    int s = (idx >> 6) & 1;
    int t = idx >> 7;
    int col = t * 16 + (l & 15);
    int k0  = s * 32 + (l >> 4) * 8;
    short* dst = wsb + idx * 8;
    #pragma unroll
    for (int j = 0; j < 8; ++j)
        dst[j] = (short)f2bf(pos_emb[(k0 + j) * NPOS + col]);
}

__global__ __launch_bounds__(256, 3) void cope2d_kernel(
    const float* __restrict__ query,
    const float* __restrict__ attn_logits,
    const bf16x8* __restrict__ wsb8,
    float* __restrict__ out)
{
    __shared__ float Lf[2][16 * LTSF];   // 2 x 18688 B L-table
    __shared__ float Bs[2][4 * 256];     // 2 x 4096 B per-col wave block-sums

    const int tid  = threadIdx.x;
    const int lane = tid & 63;
    const int wave = tid >> 6;
    const int blk  = blockIdx.x;               // 0..4095
    const int bh   = blk >> 2;
    const int p0   = (blk & 3) * 4;

    int rowbase = bh * 256 + p0 * 16;
    int gb      = rowbase * 256;

    // scan group masks: contribution from lane l+k valid iff (l&3)+k <= 3
    const int l3 = lane & 3;
    const float m1 = (l3 < 3) ? 1.0f : 0.0f;
    const float m2 = (l3 < 2) ? 1.0f : 0.0f;
    const float m3 = (l3 < 1) ? 1.0f : 0.0f;

    // ---- B fragments: load ONCE, reused all 4 steps ------------------------
    bf16x8 Bf[5][2];
    #pragma unroll
    for (int u = 0; u < 5; ++u) {
        int t = wave + 4 * u;
        if (t < NT) {
            Bf[u][0] = wsb8[(t * 2 + 0) * 64 + lane];
            Bf[u][1] = wsb8[(t * 2 + 1) * 64 + lane];
        }
    }

    // ---- prologue: prefetch q (nt: evict-first) + gates --------------------
    const float* qp = query + rowbase * 64 + (lane & 15) * 64 + (lane >> 4) * 8;
    f32x4 q00 = __builtin_nontemporal_load((const f32x4*)(qp));
    f32x4 q01 = __builtin_nontemporal_load((const f32x4*)(qp + 4));
    f32x4 q10 = __builtin_nontemporal_load((const f32x4*)(qp + 32));
    f32x4 q11 = __builtin_nontemporal_load((const f32x4*)(qp + 36));
    f32x4 gnv[4];
    {
        const float* gp = attn_logits + gb + wave * 4 * 256 + lane * 4;
        #pragma unroll
        for (int j = 0; j < 4; ++j)
            gnv[j] = *(const f32x4*)(gp + j * 256);
    }

    for (int s = 0; s < 4; ++s) {
        // ---- A fragments ----------------------------------------------------
        union { bf16x8 v; unsigned u[4]; } A0, A1;
        A0.u[0] = cvt_pk_bf16(q00[0], q00[1]);
        A0.u[1] = cvt_pk_bf16(q00[2], q00[3]);
        A0.u[2] = cvt_pk_bf16(q01[0], q01[1]);
        A0.u[3] = cvt_pk_bf16(q01[2], q01[3]);
        A1.u[0] = cvt_pk_bf16(q10[0], q10[1]);
        A1.u[1] = cvt_pk_bf16(q10[2], q10[3]);
        A1.u[2] = cvt_pk_bf16(q11[0], q11[1]);
        A1.u[3] = cvt_pk_bf16(q11[2], q11[3]);

        // ---- MFMA GEMM -> Lf[s&1] ------------------------------------------
        float* Lfs = Lf[s & 1];
        #pragma unroll
        for (int u = 0; u < 5; ++u) {
            int t = wave + 4 * u;
            if (t < NT) {
                f32x4 c = {0.f, 0.f, 0.f, 0.f};
                c = __builtin_amdgcn_mfma_f32_16x16x32_bf16(A0.v, Bf[u][0], c, 0, 0, 0);
                c = __builtin_amdgcn_mfma_f32_16x16x32_bf16(A1.v, Bf[u][1], c, 0, 0, 0);
                const int col = t * 16 + (lane & 15);
                const int r0  = (lane >> 4) * 4;
                #pragma unroll
                for (int r = 0; r < 4; ++r)
                    Lfs[(r0 + r) * LTSF + col] = c[r];
            }
        }

        // ---- sigmoid (own 4 rows x 4 cols) + block-sum to LDS --------------
        f32x4 gs[4];
        #pragma unroll
        for (int j = 0; j < 4; ++j)
            #pragma unroll
            for (int c4 = 0; c4 < 4; ++c4)
                gs[j][c4] = sigmoid_f(gnv[j][c4]);
        {
            f32x4 bsv = gs[0] + gs[1] + gs[2] + gs[3];
            *(f32x4*)&Bs[s & 1][wave * 256 + lane * 4] = bsv;
        }

        const int gout = gb;

        // ---- raw barrier: drains LDS writes (table + block-sums) only ------
        asm volatile("s_waitcnt lgkmcnt(0)" ::: "memory");
        __builtin_amdgcn_s_barrier();

        // ---- SA = sum of later waves' block-sums (pos_h prefix from below) -
        f32x4 SA = {0.f, 0.f, 0.f, 0.f};
        for (int w2 = wave + 1; w2 < 4; ++w2)
            SA += *(const f32x4*)&Bs[s & 1][w2 * 256 + lane * 4];

        // ---- prefetch step s+1 ---------------------------------------------
        if (s < 3) {
            rowbase += 16;
            gb += 16 * 256;
            const float* qp2 = query + rowbase * 64 + (lane & 15) * 64 + (lane >> 4) * 8;
            q00 = __builtin_nontemporal_load((const f32x4*)(qp2));
            q01 = __builtin_nontemporal_load((const f32x4*)(qp2 + 4));
            q10 = __builtin_nontemporal_load((const f32x4*)(qp2 + 32));
            q11 = __builtin_nontemporal_load((const f32x4*)(qp2 + 36));
            const float* gp2 = attn_logits + gb + wave * 4 * 256 + lane * 4;
            #pragma unroll
            for (int j = 0; j < 4; ++j)
                gnv[j] = *(const f32x4*)(gp2 + j * 256);
        }

        // ---- phase D: own rows 4w+3..4w+0, 4 consecutive cols/lane ---------
        // pos <= 272 < 287: clamp identity; fi+1 <= 273 < 292 in-bounds.
        float a0 = SA[0], a1 = SA[1], a2 = SA[2], a3 = SA[3];
        float* op = out + gout + (wave * 4) * 256 + lane * 4;
        #pragma unroll
        for (int j = 3; j >= 0; --j) {
            float g0 = gs[j][0], g1 = gs[j][1], g2 = gs[j][2], g3 = gs[j][3];
            // local col suffix within lane
            float s3 = g3, s2 = g2 + g3, s1 = g1 + s2, s0 = g0 + s1;
            // cross-lane remainder within 4-lane group (masked row_shl)
            float R = fmaf(m1, row_shl<1>(s0),
                      fmaf(m2, row_shl<2>(s0), m3 * row_shl<3>(s0)));
            // pos_h accumulators (inclusive, rows below already in SA)
            a0 += g0; a1 += g1; a2 += g2; a3 += g3;

            float pos0 = fmaf(a0, 16.0f, s0 + R);
            float pos1 = fmaf(a1, 16.0f, s1 + R);
            float pos2 = fmaf(a2, 16.0f, s2 + R);
            float pos3 = fmaf(a3, 16.0f, s3 + R);
            int  fi0 = (int)pos0, fi1 = (int)pos1, fi2 = (int)pos2, fi3 = (int)pos3;
            float w0 = fast_fract(pos0), w1 = fast_fract(pos1);
            float w2 = fast_fract(pos2), w3 = fast_fract(pos3);

            const float* Lr = Lfs + (wave * 4 + j) * LTSF;
            float lf0 = Lr[fi0], lc0 = Lr[fi0 + 1];
            float lf1 = Lr[fi1], lc1 = Lr[fi1 + 1];
            float lf2 = Lr[fi2], lc2 = Lr[fi2 + 1];
            float lf3 = Lr[fi3], lc3 = Lr[fi3 + 1];

            f32x4 o;
            o[0] = lf0 + w0 * (lc0 - lf0);
            o[1] = lf1 + w1 * (lc1 - lf1);
            o[2] = lf2 + w2 * (lc2 - lf2);
            o[3] = lf3 + w3 * (lc3 - lf3);
            __builtin_nontemporal_store(o, (f32x4*)(op + j * 256));
        }
        // WAR on Lf[s&1]/Bs[s&1] covered by the raw barriers of steps s+1,s+2.
    }
}

extern "C" void kernel_launch(void* const* d_in, const int* in_sizes, int n_in,
                              void* d_out, int out_size, void* d_ws, size_t ws_size,
                              hipStream_t stream) {
    const float* query       = (const float*)d_in[0];
    const float* attn_logits = (const float*)d_in[1];
    const float* pos_emb     = (const float*)d_in[2];
    float* outp = (float*)d_out;
    short* wsb  = (short*)d_ws;          // NT*2*64*8 bf16 = 36 KB

    prep_kernel<<<9, 256, 0, stream>>>(pos_emb, wsb);
    cope2d_kernel<<<4096, 256, 0, stream>>>(query, attn_logits,
                                            (const bf16x8*)d_ws, outp);
}

// Round 19
// 119.699 us; speedup vs baseline: 1.1115x; 1.1115x over previous
//
#include <hip/hip_runtime.h>

// CoPE2d: B=64, NH=16, Wh=Ww=16, N=256, C=64, NPOS=288, BH=1024
// R19 = R17 (best, 119 us: 4-wave/4-step pipeline, dbuf f32 L-table, raw
// barrier, float4 phase D, nt stores, PLAIN q loads) + depth-2 gate prefetch:
// gates for step s+2 issued at step s (2 full steps of program-order slack).

#define NPOS 288
#define NT   18
#define LTSF 292         // f32 Ltab row stride (padded)

typedef __attribute__((ext_vector_type(8))) short bf16x8;
typedef __attribute__((ext_vector_type(4))) float f32x4;

__device__ __forceinline__ unsigned short f2bf(float f) {
    unsigned u = __float_as_uint(f);
    u += 0x7FFF + ((u >> 16) & 1);
    return (unsigned short)(u >> 16);
}
__device__ __forceinline__ unsigned cvt_pk_bf16(float lo, float hi) {
    unsigned r;                       // plain-loaded inputs only (R13 lesson)
    asm("v_cvt_pk_bf16_f32 %0, %1, %2" : "=v"(r) : "v"(lo), "v"(hi));
    return r;
}
__device__ __forceinline__ float fast_exp2(float x) {
    float r; asm("v_exp_f32 %0, %1" : "=v"(r) : "v"(x)); return r;
}
__device__ __forceinline__ float fast_fract(float x) {
    float r; asm("v_fract_f32 %0, %1" : "=v"(r) : "v"(x)); return r;
}
__device__ __forceinline__ float sigmoid_f(float x) {
    return __builtin_amdgcn_rcpf(1.0f + fast_exp2(x * -1.44269504088896f));
}
// row_shl:D within 16-lane DPP rows, 0 beyond row end.
template <int D>
__device__ __forceinline__ float row_shl(float v) {
    int s = __builtin_amdgcn_update_dpp(0, __float_as_int(v), 0x100 | D, 0xF, 0xF, true);
    return __int_as_float(s);
}

// ---- prep: pos_emb (64x288 f32) -> bf16 B-fragments in ws ------------------
__global__ void prep_kernel(const float* __restrict__ pos_emb,
                            short* __restrict__ wsb) {
    int idx = blockIdx.x * blockDim.x + threadIdx.x;
    if (idx >= NT * 2 * 64) return;
    int l = idx & 63;
    int s = (idx >> 6) & 1;
    int t = idx >> 7;
    int col = t * 16 + (l & 15);
    int k0  = s * 32 + (l >> 4) * 8;
    short* dst = wsb + idx * 8;
    #pragma unroll
    for (int j = 0; j < 8; ++j)
        dst[j] = (short)f2bf(pos_emb[(k0 + j) * NPOS + col]);
}

__global__ __launch_bounds__(256, 3) void cope2d_kernel(
    const float* __restrict__ query,
    const float* __restrict__ attn_logits,
    const bf16x8* __restrict__ wsb8,
    float* __restrict__ out)
{
    __shared__ float Lf[2][16 * LTSF];   // 2 x 18688 B L-table
    __shared__ float Bs[2][4 * 256];     // 2 x 4096 B per-col wave block-sums

    const int tid  = threadIdx.x;
    const int lane = tid & 63;
    const int wave = tid >> 6;
    const int blk  = blockIdx.x;               // 0..4095
    const int bh   = blk >> 2;
    const int p0   = (blk & 3) * 4;

    int rowbase = bh * 256 + p0 * 16;
    int gb      = rowbase * 256;

    // scan group masks: contribution from lane l+k valid iff (l&3)+k <= 3
    const int l3 = lane & 3;
    const float m1 = (l3 < 3) ? 1.0f : 0.0f;
    const float m2 = (l3 < 2) ? 1.0f : 0.0f;
    const float m3 = (l3 < 1) ? 1.0f : 0.0f;

    // ---- B fragments: load ONCE, reused all 4 steps ------------------------
    bf16x8 Bf[5][2];
    #pragma unroll
    for (int u = 0; u < 5; ++u) {
        int t = wave + 4 * u;
        if (t < NT) {
            Bf[u][0] = wsb8[(t * 2 + 0) * 64 + lane];
            Bf[u][1] = wsb8[(t * 2 + 1) * 64 + lane];
        }
    }

    // ---- prologue: q(step0) + gates(step0->gA, step1->gB) ------------------
    const float* qp = query + rowbase * 64 + (lane & 15) * 64 + (lane >> 4) * 8;
    f32x4 q00 = *(const f32x4*)(qp);
    f32x4 q01 = *(const f32x4*)(qp + 4);
    f32x4 q10 = *(const f32x4*)(qp + 32);
    f32x4 q11 = *(const f32x4*)(qp + 36);
    f32x4 gA[4], gB[4];
    {
        const float* gp = attn_logits + gb + wave * 4 * 256 + lane * 4;
        #pragma unroll
        for (int j = 0; j < 4; ++j)
            gA[j] = *(const f32x4*)(gp + j * 256);          // step 0
        #pragma unroll
        for (int j = 0; j < 4; ++j)
            gB[j] = *(const f32x4*)(gp + 4096 + j * 256);   // step 1
    }

    #pragma unroll
    for (int s = 0; s < 4; ++s) {
        f32x4 (&gc)[4] = (s & 1) ? gB : gA;    // folds under full unroll

        // ---- A fragments ----------------------------------------------------
        union { bf16x8 v; unsigned u[4]; } A0, A1;
        A0.u[0] = cvt_pk_bf16(q00[0], q00[1]);
        A0.u[1] = cvt_pk_bf16(q00[2], q00[3]);
        A0.u[2] = cvt_pk_bf16(q01[0], q01[1]);
        A0.u[3] = cvt_pk_bf16(q01[2], q01[3]);
        A1.u[0] = cvt_pk_bf16(q10[0], q10[1]);
        A1.u[1] = cvt_pk_bf16(q10[2], q10[3]);
        A1.u[2] = cvt_pk_bf16(q11[0], q11[1]);
        A1.u[3] = cvt_pk_bf16(q11[2], q11[3]);

        // ---- MFMA GEMM -> Lf[s&1] ------------------------------------------
        float* Lfs = Lf[s & 1];
        #pragma unroll
        for (int u = 0; u < 5; ++u) {
            int t = wave + 4 * u;
            if (t < NT) {
                f32x4 c = {0.f, 0.f, 0.f, 0.f};
                c = __builtin_amdgcn_mfma_f32_16x16x32_bf16(A0.v, Bf[u][0], c, 0, 0, 0);
                c = __builtin_amdgcn_mfma_f32_16x16x32_bf16(A1.v, Bf[u][1], c, 0, 0, 0);
                const int col = t * 16 + (lane & 15);
                const int r0  = (lane >> 4) * 4;
                #pragma unroll
                for (int r = 0; r < 4; ++r)
                    Lfs[(r0 + r) * LTSF + col] = c[r];
            }
        }

        // ---- sigmoid (own 4 rows x 4 cols) + block-sum to LDS --------------
        f32x4 gs[4];
        #pragma unroll
        for (int j = 0; j < 4; ++j)
            #pragma unroll
            for (int c4 = 0; c4 < 4; ++c4)
                gs[j][c4] = sigmoid_f(gc[j][c4]);
        {
            f32x4 bsv = gs[0] + gs[1] + gs[2] + gs[3];
            *(f32x4*)&Bs[s & 1][wave * 256 + lane * 4] = bsv;
        }

        const int gout = gb;

        // ---- raw barrier: drains LDS writes (table + block-sums) only ------
        asm volatile("s_waitcnt lgkmcnt(0)" ::: "memory");
        __builtin_amdgcn_s_barrier();

        // ---- SA = sum of later waves' block-sums (pos_h prefix from below) -
        f32x4 SA = {0.f, 0.f, 0.f, 0.f};
        for (int w2 = wave + 1; w2 < 4; ++w2)
            SA += *(const f32x4*)&Bs[s & 1][w2 * 256 + lane * 4];

        // ---- prefetch: q for s+1 (depth 1), gates for s+2 (depth 2) --------
        if (s < 3) {
            const float* qp2 = query + (rowbase + 16) * 64
                             + (lane & 15) * 64 + (lane >> 4) * 8;
            q00 = *(const f32x4*)(qp2);
            q01 = *(const f32x4*)(qp2 + 4);
            q10 = *(const f32x4*)(qp2 + 32);
            q11 = *(const f32x4*)(qp2 + 36);
        }
        if (s < 2) {   // refill the regs sigmoid just consumed (gc dead now)
            const float* gp2 = attn_logits + gb + 2 * 4096
                             + wave * 4 * 256 + lane * 4;
            #pragma unroll
            for (int j = 0; j < 4; ++j)
                gc[j] = *(const f32x4*)(gp2 + j * 256);
        }

        // ---- phase D: own rows 4w+3..4w+0, 4 consecutive cols/lane ---------
        // pos <= 272 < 287: clamp identity; fi+1 <= 273 < 292 in-bounds.
        float a0 = SA[0], a1 = SA[1], a2 = SA[2], a3 = SA[3];
        float* op = out + gout + (wave * 4) * 256 + lane * 4;
        #pragma unroll
        for (int j = 3; j >= 0; --j) {
            float g0 = gs[j][0], g1 = gs[j][1], g2 = gs[j][2], g3 = gs[j][3];
            // local col suffix within lane
            float s3 = g3, s2 = g2 + g3, s1 = g1 + s2, s0 = g0 + s1;
            // cross-lane remainder within 4-lane group (masked row_shl)
            float R = fmaf(m1, row_shl<1>(s0),
                      fmaf(m2, row_shl<2>(s0), m3 * row_shl<3>(s0)));
            // pos_h accumulators (inclusive, rows below already in SA)
            a0 += g0; a1 += g1; a2 += g2; a3 += g3;

            float pos0 = fmaf(a0, 16.0f, s0 + R);
            float pos1 = fmaf(a1, 16.0f, s1 + R);
            float pos2 = fmaf(a2, 16.0f, s2 + R);
            float pos3 = fmaf(a3, 16.0f, s3 + R);
            int  fi0 = (int)pos0, fi1 = (int)pos1, fi2 = (int)pos2, fi3 = (int)pos3;
            float w0 = fast_fract(pos0), w1 = fast_fract(pos1);
            float w2 = fast_fract(pos2), w3 = fast_fract(pos3);

            const float* Lr = Lfs + (wave * 4 + j) * LTSF;
            float lf0 = Lr[fi0], lc0 = Lr[fi0 + 1];
            float lf1 = Lr[fi1], lc1 = Lr[fi1 + 1];
            float lf2 = Lr[fi2], lc2 = Lr[fi2 + 1];
            float lf3 = Lr[fi3], lc3 = Lr[fi3 + 1];

            f32x4 o;
            o[0] = lf0 + w0 * (lc0 - lf0);
            o[1] = lf1 + w1 * (lc1 - lf1);
            o[2] = lf2 + w2 * (lc2 - lf2);
            o[3] = lf3 + w3 * (lc3 - lf3);
            __builtin_nontemporal_store(o, (f32x4*)(op + j * 256));
        }

        rowbase += 16;
        gb += 4096;
        // WAR on Lf[s&1]/Bs[s&1] covered by the raw barriers of steps s+1,s+2.
    }
}

extern "C" void kernel_launch(void* const* d_in, const int* in_sizes, int n_in,
                              void* d_out, int out_size, void* d_ws, size_t ws_size,
                              hipStream_t stream) {
    const float* query       = (const float*)d_in[0];
    const float* attn_logits = (const float*)d_in[1];
    const float* pos_emb     = (const float*)d_in[2];
    float* outp = (float*)d_out;
    short* wsb  = (short*)d_ws;          // NT*2*64*8 bf16 = 36 KB

    prep_kernel<<<9, 256, 0, stream>>>(pos_emb, wsb);
    cope2d_kernel<<<4096, 256, 0, stream>>>(query, attn_logits,
                                            (const bf16x8*)d_ws, outp);
}